// Round 1
// baseline (676.299 us; speedup 1.0000x reference)
//
#include <hip/hip_runtime.h>
#include <hip/hip_bf16.h>

// Problem constants
#define B_SZ   16384
#define DIN    2048
#define H1_SZ  512
#define H2_SZ  128
#define N_EXP  8
#define N_CLS  10
#define N1     4608   // 8*512 experts + 512 gate
#define N2     1152   // 8*128 experts + 128 gate

typedef __attribute__((ext_vector_type(8))) __bf16 bf16x8;
typedef __attribute__((ext_vector_type(4))) float  floatx4;
typedef __attribute__((ext_vector_type(4))) short  short4v;
typedef __attribute__((ext_vector_type(8))) short  short8v;

__device__ __forceinline__ float bf2f(short s) {
  unsigned int u = ((unsigned int)(unsigned short)s) << 16;
  float f; __builtin_memcpy(&f, &u, 4); return f;
}

// ---------------------------------------------------------------------------
// Prep 1: features = concat(fs, fp) -> bf16 X[B][DIN]
// ---------------------------------------------------------------------------
__global__ void convert_features_kernel(const float* __restrict__ fs,
                                        const float* __restrict__ fp,
                                        __hip_bfloat16* __restrict__ X) {
  const int nf4 = B_SZ * (DIN / 4);          // 8,388,608 float4 chunks
  const float4* fs4 = (const float4*)fs;
  const float4* fp4 = (const float4*)fp;
  for (int i = blockIdx.x * blockDim.x + threadIdx.x; i < nf4;
       i += gridDim.x * blockDim.x) {
    int c = i & 511;                         // DIN/4 = 512 chunks per row
    int row = i >> 9;
    float4 v = (c < 256) ? fs4[(size_t)row * 256 + c]
                         : fp4[(size_t)row * 256 + (c - 256)];
    union { short4v v4; __hip_bfloat16 h[4]; } u;
    u.h[0] = __float2bfloat16(v.x);
    u.h[1] = __float2bfloat16(v.y);
    u.h[2] = __float2bfloat16(v.z);
    u.h[3] = __float2bfloat16(v.w);
    *(short4v*)(X + (size_t)i * 4) = u.v4;
  }
}

// ---------------------------------------------------------------------------
// Prep 2: transpose-convert weights to B^T layout (rows = n, stride K), bf16.
// Source: expert_src [E][K][H], gate_src [K][H]. Out rows: n = e*H + h for
// e<E, then gate rows at n in [E*H, E*H+H).
// ---------------------------------------------------------------------------
__global__ void transpose_convert_kernel(const float* __restrict__ expert_src,
                                         const float* __restrict__ gate_src,
                                         int K, int H, int E,
                                         __hip_bfloat16* __restrict__ out) {
  __shared__ float t[32][33];
  int k0 = blockIdx.x * 32;
  int n0 = blockIdx.y * 32;   // 32 | H, so a tile never straddles experts
  int e = n0 / H;
  const float* src; int h0;
  if (e < E) { src = expert_src + (size_t)e * K * H; h0 = n0 - e * H; }
  else       { src = gate_src;                       h0 = n0 - E * H; }
  int tx = threadIdx.x, ty = threadIdx.y;
  #pragma unroll
  for (int j = 0; j < 4; ++j) {
    int r = ty + j * 8;
    t[r][tx] = src[(size_t)(k0 + r) * H + h0 + tx];
  }
  __syncthreads();
  #pragma unroll
  for (int j = 0; j < 4; ++j) {
    int r = ty + j * 8;
    out[(size_t)(n0 + r) * K + k0 + tx] = __float2bfloat16(t[tx][r]);
  }
}

// ---------------------------------------------------------------------------
// MFMA GEMM core: C[128x128] = relu(A[128xK] * B[KxN-slice] + bias), bf16 out.
// A row-major [m][k]; BT row-major [n][k] (i.e. B^T); 256 threads, 4 waves in
// 2x2, each wave 64x64 via 4x4 tiles of 16x16x32 MFMA. BK=64, 2-barrier loop,
// global_load_lds width-16 staging (lane-ordered LDS layout, no padding).
// ---------------------------------------------------------------------------
__device__ __forceinline__ void gemm_core(
    const __hip_bfloat16* __restrict__ A,  int lda,
    const __hip_bfloat16* __restrict__ BT, int K,
    const float* __restrict__ bias,
    __hip_bfloat16* __restrict__ O, int ldo) {
  __shared__ __align__(16) __hip_bfloat16 As[128 * 64];
  __shared__ __align__(16) __hip_bfloat16 Bs[128 * 64];

  const int tid  = threadIdx.x;
  const int lane = tid & 63;
  const int wave = tid >> 6;
  const int wm   = (wave >> 1) * 64;
  const int wn   = (wave & 1) * 64;
  const int lrow  = lane & 15;
  const int lquad = lane >> 4;

  floatx4 acc[4][4] = {};

  for (int k0 = 0; k0 < K; k0 += 64) {
    #pragma unroll
    for (int j = 0; j < 4; ++j) {
      int chunk = j * 256 + tid;       // 0..1023 chunks of 8 bf16 (16 B)
      int mi = chunk >> 3;             // tile row 0..127
      int kk = (chunk & 7) * 8;        // tile col 0..56
      __builtin_amdgcn_global_load_lds(
          (const __attribute__((address_space(1))) unsigned int*)(A + (size_t)mi * lda + k0 + kk),
          (__attribute__((address_space(3))) unsigned int*)(As + chunk * 8),
          16, 0, 0);
      __builtin_amdgcn_global_load_lds(
          (const __attribute__((address_space(1))) unsigned int*)(BT + (size_t)mi * K + k0 + kk),
          (__attribute__((address_space(3))) unsigned int*)(Bs + chunk * 8),
          16, 0, 0);
    }
    __syncthreads();
    #pragma unroll
    for (int ks = 0; ks < 2; ++ks) {
      bf16x8 a[4], b[4];
      #pragma unroll
      for (int t = 0; t < 4; ++t) {
        a[t] = *(const bf16x8*)(As + (wm + t * 16 + lrow) * 64 + ks * 32 + lquad * 8);
        b[t] = *(const bf16x8*)(Bs + (wn + t * 16 + lrow) * 64 + ks * 32 + lquad * 8);
      }
      #pragma unroll
      for (int mt = 0; mt < 4; ++mt)
        #pragma unroll
        for (int nt = 0; nt < 4; ++nt)
          acc[mt][nt] = __builtin_amdgcn_mfma_f32_16x16x32_bf16(
              a[mt], b[nt], acc[mt][nt], 0, 0, 0);
    }
    __syncthreads();
  }

  // epilogue: bias + relu -> bf16. C/D layout: col = lane&15, row = quad*4+r.
  #pragma unroll
  for (int nt = 0; nt < 4; ++nt) {
    int col = wn + nt * 16 + lrow;
    float bv = bias[col];
    #pragma unroll
    for (int mt = 0; mt < 4; ++mt) {
      #pragma unroll
      for (int r = 0; r < 4; ++r) {
        int row = wm + mt * 16 + lquad * 4 + r;
        float v = acc[mt][nt][r] + bv;
        v = v > 0.f ? v : 0.f;
        O[(size_t)row * ldo + col] = __float2bfloat16(v);
      }
    }
  }
}

// Layer 1: X[B][2048] @ W1T^T -> relu -> H1[B][4608]
__global__ __launch_bounds__(256, 2) void gemm1_kernel(
    const __hip_bfloat16* __restrict__ X, const __hip_bfloat16* __restrict__ W1T,
    const float* __restrict__ eb1, const float* __restrict__ gb1,
    __hip_bfloat16* __restrict__ H1) {
  int m0 = blockIdx.y * 128;
  int n0 = blockIdx.x * 128;
  const float* bias = (n0 < N_EXP * H1_SZ) ? (eb1 + n0) : (gb1 + (n0 - N_EXP * H1_SZ));
  gemm_core(X + (size_t)m0 * DIN, DIN,
            W1T + (size_t)n0 * DIN, DIN,
            bias,
            H1 + (size_t)m0 * N1 + n0, N1);
}

// Layer 2: per z in 0..8: H1 block [B][512] @ W2T[z]^T -> relu -> H2 block [B][128]
__global__ __launch_bounds__(256, 2) void gemm2_kernel(
    const __hip_bfloat16* __restrict__ H1, const __hip_bfloat16* __restrict__ W2T,
    const float* __restrict__ eb2, const float* __restrict__ gb2,
    __hip_bfloat16* __restrict__ H2) {
  int m0 = blockIdx.y * 128;
  int z  = blockIdx.z;                 // 0..7 experts, 8 = gate
  const float* bias = (z < N_EXP) ? (eb2 + z * H2_SZ) : gb2;
  gemm_core(H1 + (size_t)m0 * N1 + z * H1_SZ, N1,
            W2T + (size_t)z * H2_SZ * H1_SZ, H1_SZ,
            bias,
            H2 + (size_t)m0 * N2 + z * H2_SZ, N2);
}

// ---------------------------------------------------------------------------
// Layer 3 fused: gate logits + softmax, expert logits + log_softmax, weighted
// sum. 8 threads per batch row (thread j = expert j and gate col j).
// ---------------------------------------------------------------------------
__global__ __launch_bounds__(256) void layer3_kernel(
    const __hip_bfloat16* __restrict__ H2,
    const float* __restrict__ gW3, const float* __restrict__ gb3,
    const float* __restrict__ eW3, const float* __restrict__ eb3,
    float* __restrict__ out, float* __restrict__ gate_out) {
  int tid  = threadIdx.x;
  int j    = tid & 7;
  int rloc = tid >> 3;                             // 0..31
  long row = (long)blockIdx.x * 32 + rloc;
  const __hip_bfloat16* hrow = H2 + row * N2;

  float accg = 0.f;
  float acc[N_CLS];
  #pragma unroll
  for (int c = 0; c < N_CLS; ++c) acc[c] = 0.f;

  #pragma unroll 4
  for (int k8 = 0; k8 < 16; ++k8) {
    short8v hg8 = *(const short8v*)(hrow + N_EXP * H2_SZ + k8 * 8);  // gate block
    short8v he8 = *(const short8v*)(hrow + j * H2_SZ + k8 * 8);      // expert j
    #pragma unroll
    for (int t = 0; t < 8; ++t) {
      int k = k8 * 8 + t;
      float hg = bf2f(hg8[t]);
      float he = bf2f(he8[t]);
      accg += hg * gW3[k * N_EXP + j];
      const float* w = eW3 + (size_t)(j * H2_SZ + k) * N_CLS;
      #pragma unroll
      for (int c = 0; c < N_CLS; ++c) acc[c] += he * w[c];
    }
  }

  // gate softmax across the 8 threads of this row
  float gj = accg + gb3[j];
  float mx = gj;
  mx = fmaxf(mx, __shfl_xor(mx, 1));
  mx = fmaxf(mx, __shfl_xor(mx, 2));
  mx = fmaxf(mx, __shfl_xor(mx, 4));
  float ex = __expf(gj - mx);
  float s = ex;
  s += __shfl_xor(s, 1);
  s += __shfl_xor(s, 2);
  s += __shfl_xor(s, 4);
  float gp = ex / s;

  // expert-local log_softmax over 10 classes
  float lg[N_CLS];
  float lm = -1e30f;
  #pragma unroll
  for (int c = 0; c < N_CLS; ++c) {
    lg[c] = acc[c] + eb3[j * N_CLS + c];
    lm = fmaxf(lm, lg[c]);
  }
  float es = 0.f;
  #pragma unroll
  for (int c = 0; c < N_CLS; ++c) es += __expf(lg[c] - lm);
  float lse = lm + __logf(es);

  float o[N_CLS];
  #pragma unroll
  for (int c = 0; c < N_CLS; ++c) o[c] = gp * (lg[c] - lse);
  #pragma unroll
  for (int c = 0; c < N_CLS; ++c) {
    o[c] += __shfl_xor(o[c], 1);
    o[c] += __shfl_xor(o[c], 2);
    o[c] += __shfl_xor(o[c], 4);
  }

  gate_out[row * N_EXP + j] = gp;
  if (j == 0) {
    #pragma unroll
    for (int c = 0; c < N_CLS; ++c) out[row * N_CLS + c] = o[c];
  }
}

// ---------------------------------------------------------------------------
extern "C" void kernel_launch(void* const* d_in, const int* in_sizes, int n_in,
                              void* d_out, int out_size, void* d_ws, size_t ws_size,
                              hipStream_t stream) {
  const float* fs  = (const float*)d_in[0];
  const float* fp  = (const float*)d_in[1];
  const float* gW1 = (const float*)d_in[2];
  const float* gb1 = (const float*)d_in[3];
  const float* gW2 = (const float*)d_in[4];
  const float* gb2 = (const float*)d_in[5];
  const float* gW3 = (const float*)d_in[6];
  const float* gb3 = (const float*)d_in[7];
  const float* eW1 = (const float*)d_in[8];
  const float* eb1 = (const float*)d_in[9];
  const float* eW2 = (const float*)d_in[10];
  const float* eb2 = (const float*)d_in[11];
  const float* eW3 = (const float*)d_in[12];
  const float* eb3 = (const float*)d_in[13];
  float* out = (float*)d_out;                   // [B,10] then [B,8]

  // workspace layout (bytes):
  //   X   : 0          .. 67,108,864   (B*2048 bf16)  -- aliased by H2 later
  //   W1T : 67,108,864 .. 85,983,232   (4608*2048 bf16)
  //   W2T : 85,983,232 .. 87,162,880   (1152*512 bf16)
  //   H1  : 87,162,880 .. 238,157,824  (B*4608 bf16)
  char* ws = (char*)d_ws;
  __hip_bfloat16* X   = (__hip_bfloat16*)ws;
  __hip_bfloat16* H2  = X;   // alias: X dead after gemm1, H2 fits inside
  __hip_bfloat16* W1T = (__hip_bfloat16*)(ws + 67108864);
  __hip_bfloat16* W2T = (__hip_bfloat16*)(ws + 85983232);
  __hip_bfloat16* H1  = (__hip_bfloat16*)(ws + 87162880);

  convert_features_kernel<<<2048, 256, 0, stream>>>(fs, fp, X);
  transpose_convert_kernel<<<dim3(DIN / 32, N1 / 32), dim3(32, 8), 0, stream>>>(
      eW1, gW1, DIN, H1_SZ, N_EXP, W1T);
  transpose_convert_kernel<<<dim3(H1_SZ / 32, N2 / 32), dim3(32, 8), 0, stream>>>(
      eW2, gW2, H1_SZ, H2_SZ, N_EXP, W2T);
  gemm1_kernel<<<dim3(N1 / 128, B_SZ / 128), 256, 0, stream>>>(X, W1T, eb1, gb1, H1);
  gemm2_kernel<<<dim3(1, B_SZ / 128, N_EXP + 1), 256, 0, stream>>>(H1, W2T, eb2, gb2, H2);
  layer3_kernel<<<B_SZ / 32, 256, 0, stream>>>(H2, gW3, gb3, eW3, eb3,
                                               out, out + (size_t)B_SZ * N_CLS);
}

// Round 2
// 602.311 us; speedup vs baseline: 1.1228x; 1.1228x over previous
//
#include <hip/hip_runtime.h>
#include <hip/hip_bf16.h>

// Problem constants
#define B_SZ   16384
#define DIN    2048
#define H1_SZ  512
#define H2_SZ  128
#define N_EXP  8
#define N_CLS  10
#define N1     4608   // 8*512 experts + 512 gate
#define N2     1152   // 8*128 experts + 128 gate

typedef __attribute__((ext_vector_type(8))) __bf16 bf16x8;
typedef __attribute__((ext_vector_type(4))) float  floatx4;
typedef __attribute__((ext_vector_type(4))) short  short4v;
typedef __attribute__((ext_vector_type(8))) short  short8v;

__device__ __forceinline__ float bf2f(short s) {
  unsigned int u = ((unsigned int)(unsigned short)s) << 16;
  float f; __builtin_memcpy(&f, &u, 4); return f;
}

// ---------------------------------------------------------------------------
// Prep 1: features = concat(fs, fp) -> bf16 X[B][DIN]
// ---------------------------------------------------------------------------
__global__ void convert_features_kernel(const float* __restrict__ fs,
                                        const float* __restrict__ fp,
                                        __hip_bfloat16* __restrict__ X) {
  const int nf4 = B_SZ * (DIN / 4);          // 8,388,608 float4 chunks
  const float4* fs4 = (const float4*)fs;
  const float4* fp4 = (const float4*)fp;
  for (int i = blockIdx.x * blockDim.x + threadIdx.x; i < nf4;
       i += gridDim.x * blockDim.x) {
    int c = i & 511;                         // DIN/4 = 512 chunks per row
    int row = i >> 9;
    float4 v = (c < 256) ? fs4[(size_t)row * 256 + c]
                         : fp4[(size_t)row * 256 + (c - 256)];
    union { short4v v4; __hip_bfloat16 h[4]; } u;
    u.h[0] = __float2bfloat16(v.x);
    u.h[1] = __float2bfloat16(v.y);
    u.h[2] = __float2bfloat16(v.z);
    u.h[3] = __float2bfloat16(v.w);
    *(short4v*)(X + (size_t)i * 4) = u.v4;
  }
}

// ---------------------------------------------------------------------------
// Prep 2: transpose-convert weights to B^T layout (rows = n, stride K), bf16.
// Source: expert_src [E][K][H], gate_src [K][H]. Out rows: n = e*H + h for
// e<E, then gate rows at n in [E*H, E*H+H).
// ---------------------------------------------------------------------------
__global__ void transpose_convert_kernel(const float* __restrict__ expert_src,
                                         const float* __restrict__ gate_src,
                                         int K, int H, int E,
                                         __hip_bfloat16* __restrict__ out) {
  __shared__ float t[32][33];
  int k0 = blockIdx.x * 32;
  int n0 = blockIdx.y * 32;   // 32 | H, so a tile never straddles experts
  int e = n0 / H;
  const float* src; int h0;
  if (e < E) { src = expert_src + (size_t)e * K * H; h0 = n0 - e * H; }
  else       { src = gate_src;                       h0 = n0 - E * H; }
  int tx = threadIdx.x, ty = threadIdx.y;
  #pragma unroll
  for (int j = 0; j < 4; ++j) {
    int r = ty + j * 8;
    t[r][tx] = src[(size_t)(k0 + r) * H + h0 + tx];
  }
  __syncthreads();
  #pragma unroll
  for (int j = 0; j < 4; ++j) {
    int r = ty + j * 8;
    out[(size_t)(n0 + r) * K + k0 + tx] = __float2bfloat16(t[tx][r]);
  }
}

// ---------------------------------------------------------------------------
// MFMA GEMM core: C[128x128] = relu(A[128xK] * B[KxN-slice] + bias), bf16 out.
// A row-major [m][k]; BT row-major [n][k] (i.e. B^T); 256 threads, 4 waves in
// 2x2, each wave 64x64 via 4x4 tiles of 16x16x32 MFMA. BK=64, 2-barrier loop,
// global_load_lds width-16 staging.
//
// LDS layout: XOR-swizzled chunks. Row stride is 64 bf16 = 128 B = exactly 32
// banks, so an unswizzled fragment read is a 16-way bank conflict (measured:
// R0 SQ_LDS_BANK_CONFLICT = 1.13e8, ~12 extra cyc per ds_read_b128). Slot
// (mi, cs) holds logical 16B chunk (cs ^ (mi&7)) of row mi. LDS destination
// of global_load_lds stays linear (wave base + lane*16 constraint); only the
// per-lane GLOBAL source address is permuted (within a 128B segment, so
// coalescing is preserved). Fragment reads then spread across all 8 bank
// groups, 2 lanes each = conflict-free.
// ---------------------------------------------------------------------------
__device__ __forceinline__ void gemm_core(
    const __hip_bfloat16* __restrict__ A,  int lda,
    const __hip_bfloat16* __restrict__ BT, int K,
    const float* __restrict__ bias,
    __hip_bfloat16* __restrict__ O, int ldo) {
  __shared__ __align__(16) __hip_bfloat16 As[128 * 64];
  __shared__ __align__(16) __hip_bfloat16 Bs[128 * 64];

  const int tid  = threadIdx.x;
  const int lane = tid & 63;
  const int wave = tid >> 6;
  const int wm   = (wave >> 1) * 64;
  const int wn   = (wave & 1) * 64;
  const int lrow  = lane & 15;
  const int lquad = lane >> 4;

  floatx4 acc[4][4] = {};

  for (int k0 = 0; k0 < K; k0 += 64) {
    #pragma unroll
    for (int j = 0; j < 4; ++j) {
      int chunk = j * 256 + tid;       // 0..1023 chunks of 8 bf16 (16 B)
      int mi = chunk >> 3;             // tile row 0..127
      int cs = chunk & 7;              // stored chunk slot 0..7
      int cl = cs ^ (mi & 7);          // logical k-chunk held in this slot
      __builtin_amdgcn_global_load_lds(
          (const __attribute__((address_space(1))) unsigned int*)(A + (size_t)mi * lda + k0 + cl * 8),
          (__attribute__((address_space(3))) unsigned int*)(As + chunk * 8),
          16, 0, 0);
      __builtin_amdgcn_global_load_lds(
          (const __attribute__((address_space(1))) unsigned int*)(BT + (size_t)mi * K + k0 + cl * 8),
          (__attribute__((address_space(3))) unsigned int*)(Bs + chunk * 8),
          16, 0, 0);
    }
    __syncthreads();
    #pragma unroll
    for (int ks = 0; ks < 2; ++ks) {
      bf16x8 a[4], b[4];
      #pragma unroll
      for (int t = 0; t < 4; ++t) {
        int ar = wm + t * 16 + lrow;
        int br = wn + t * 16 + lrow;
        int ca = (ks * 4 + lquad) ^ (ar & 7);   // swizzled chunk slot
        int cb = (ks * 4 + lquad) ^ (br & 7);
        a[t] = *(const bf16x8*)(As + ar * 64 + ca * 8);
        b[t] = *(const bf16x8*)(Bs + br * 64 + cb * 8);
      }
      #pragma unroll
      for (int mt = 0; mt < 4; ++mt)
        #pragma unroll
        for (int nt = 0; nt < 4; ++nt)
          acc[mt][nt] = __builtin_amdgcn_mfma_f32_16x16x32_bf16(
              a[mt], b[nt], acc[mt][nt], 0, 0, 0);
    }
    __syncthreads();
  }

  // epilogue: bias + relu -> bf16. C/D layout: col = lane&15, row = quad*4+r.
  #pragma unroll
  for (int nt = 0; nt < 4; ++nt) {
    int col = wn + nt * 16 + lrow;
    float bv = bias[col];
    #pragma unroll
    for (int mt = 0; mt < 4; ++mt) {
      #pragma unroll
      for (int r = 0; r < 4; ++r) {
        int row = wm + mt * 16 + lquad * 4 + r;
        float v = acc[mt][nt][r] + bv;
        v = v > 0.f ? v : 0.f;
        O[(size_t)row * ldo + col] = __float2bfloat16(v);
      }
    }
  }
}

// Layer 1: X[B][2048] @ W1T^T -> relu -> H1[B][4608]
__global__ __launch_bounds__(256, 2) void gemm1_kernel(
    const __hip_bfloat16* __restrict__ X, const __hip_bfloat16* __restrict__ W1T,
    const float* __restrict__ eb1, const float* __restrict__ gb1,
    __hip_bfloat16* __restrict__ H1) {
  int m0 = blockIdx.y * 128;
  int n0 = blockIdx.x * 128;
  const float* bias = (n0 < N_EXP * H1_SZ) ? (eb1 + n0) : (gb1 + (n0 - N_EXP * H1_SZ));
  gemm_core(X + (size_t)m0 * DIN, DIN,
            W1T + (size_t)n0 * DIN, DIN,
            bias,
            H1 + (size_t)m0 * N1 + n0, N1);
}

// Layer 2: per z in 0..8: H1 block [B][512] @ W2T[z]^T -> relu -> H2 block [B][128]
__global__ __launch_bounds__(256, 2) void gemm2_kernel(
    const __hip_bfloat16* __restrict__ H1, const __hip_bfloat16* __restrict__ W2T,
    const float* __restrict__ eb2, const float* __restrict__ gb2,
    __hip_bfloat16* __restrict__ H2) {
  int m0 = blockIdx.y * 128;
  int z  = blockIdx.z;                 // 0..7 experts, 8 = gate
  const float* bias = (z < N_EXP) ? (eb2 + z * H2_SZ) : gb2;
  gemm_core(H1 + (size_t)m0 * N1 + z * H1_SZ, N1,
            W2T + (size_t)z * H2_SZ * H1_SZ, H1_SZ,
            bias,
            H2 + (size_t)m0 * N2 + z * H2_SZ, N2);
}

// ---------------------------------------------------------------------------
// Layer 3 fused: gate logits + softmax, expert logits + log_softmax, weighted
// sum. 8 threads per batch row (thread j = expert j and gate col j).
// ---------------------------------------------------------------------------
__global__ __launch_bounds__(256) void layer3_kernel(
    const __hip_bfloat16* __restrict__ H2,
    const float* __restrict__ gW3, const float* __restrict__ gb3,
    const float* __restrict__ eW3, const float* __restrict__ eb3,
    float* __restrict__ out, float* __restrict__ gate_out) {
  int tid  = threadIdx.x;
  int j    = tid & 7;
  int rloc = tid >> 3;                             // 0..31
  long row = (long)blockIdx.x * 32 + rloc;
  const __hip_bfloat16* hrow = H2 + row * N2;

  float accg = 0.f;
  float acc[N_CLS];
  #pragma unroll
  for (int c = 0; c < N_CLS; ++c) acc[c] = 0.f;

  #pragma unroll 4
  for (int k8 = 0; k8 < 16; ++k8) {
    short8v hg8 = *(const short8v*)(hrow + N_EXP * H2_SZ + k8 * 8);  // gate block
    short8v he8 = *(const short8v*)(hrow + j * H2_SZ + k8 * 8);      // expert j
    #pragma unroll
    for (int t = 0; t < 8; ++t) {
      int k = k8 * 8 + t;
      float hg = bf2f(hg8[t]);
      float he = bf2f(he8[t]);
      accg += hg * gW3[k * N_EXP + j];
      const float* w = eW3 + (size_t)(j * H2_SZ + k) * N_CLS;
      #pragma unroll
      for (int c = 0; c < N_CLS; ++c) acc[c] += he * w[c];
    }
  }

  // gate softmax across the 8 threads of this row
  float gj = accg + gb3[j];
  float mx = gj;
  mx = fmaxf(mx, __shfl_xor(mx, 1));
  mx = fmaxf(mx, __shfl_xor(mx, 2));
  mx = fmaxf(mx, __shfl_xor(mx, 4));
  float ex = __expf(gj - mx);
  float s = ex;
  s += __shfl_xor(s, 1);
  s += __shfl_xor(s, 2);
  s += __shfl_xor(s, 4);
  float gp = ex / s;

  // expert-local log_softmax over 10 classes
  float lg[N_CLS];
  float lm = -1e30f;
  #pragma unroll
  for (int c = 0; c < N_CLS; ++c) {
    lg[c] = acc[c] + eb3[j * N_CLS + c];
    lm = fmaxf(lm, lg[c]);
  }
  float es = 0.f;
  #pragma unroll
  for (int c = 0; c < N_CLS; ++c) es += __expf(lg[c] - lm);
  float lse = lm + __logf(es);

  float o[N_CLS];
  #pragma unroll
  for (int c = 0; c < N_CLS; ++c) o[c] = gp * (lg[c] - lse);
  #pragma unroll
  for (int c = 0; c < N_CLS; ++c) {
    o[c] += __shfl_xor(o[c], 1);
    o[c] += __shfl_xor(o[c], 2);
    o[c] += __shfl_xor(o[c], 4);
  }

  gate_out[row * N_EXP + j] = gp;
  if (j == 0) {
    #pragma unroll
    for (int c = 0; c < N_CLS; ++c) out[row * N_CLS + c] = o[c];
  }
}

// ---------------------------------------------------------------------------
extern "C" void kernel_launch(void* const* d_in, const int* in_sizes, int n_in,
                              void* d_out, int out_size, void* d_ws, size_t ws_size,
                              hipStream_t stream) {
  const float* fs  = (const float*)d_in[0];
  const float* fp  = (const float*)d_in[1];
  const float* gW1 = (const float*)d_in[2];
  const float* gb1 = (const float*)d_in[3];
  const float* gW2 = (const float*)d_in[4];
  const float* gb2 = (const float*)d_in[5];
  const float* gW3 = (const float*)d_in[6];
  const float* gb3 = (const float*)d_in[7];
  const float* eW1 = (const float*)d_in[8];
  const float* eb1 = (const float*)d_in[9];
  const float* eW2 = (const float*)d_in[10];
  const float* eb2 = (const float*)d_in[11];
  const float* eW3 = (const float*)d_in[12];
  const float* eb3 = (const float*)d_in[13];
  float* out = (float*)d_out;                   // [B,10] then [B,8]

  // workspace layout (bytes):
  //   X   : 0          .. 67,108,864   (B*2048 bf16)  -- aliased by H2 later
  //   W1T : 67,108,864 .. 85,983,232   (4608*2048 bf16)
  //   W2T : 85,983,232 .. 87,162,880   (1152*512 bf16)
  //   H1  : 87,162,880 .. 238,157,824  (B*4608 bf16)
  char* ws = (char*)d_ws;
  __hip_bfloat16* X   = (__hip_bfloat16*)ws;
  __hip_bfloat16* H2  = X;   // alias: X dead after gemm1, H2 fits inside
  __hip_bfloat16* W1T = (__hip_bfloat16*)(ws + 67108864);
  __hip_bfloat16* W2T = (__hip_bfloat16*)(ws + 85983232);
  __hip_bfloat16* H1  = (__hip_bfloat16*)(ws + 87162880);

  convert_features_kernel<<<2048, 256, 0, stream>>>(fs, fp, X);
  transpose_convert_kernel<<<dim3(DIN / 32, N1 / 32), dim3(32, 8), 0, stream>>>(
      eW1, gW1, DIN, H1_SZ, N_EXP, W1T);
  transpose_convert_kernel<<<dim3(H1_SZ / 32, N2 / 32), dim3(32, 8), 0, stream>>>(
      eW2, gW2, H1_SZ, H2_SZ, N_EXP, W2T);
  gemm1_kernel<<<dim3(N1 / 128, B_SZ / 128), 256, 0, stream>>>(X, W1T, eb1, gb1, H1);
  gemm2_kernel<<<dim3(1, B_SZ / 128, N_EXP + 1), 256, 0, stream>>>(H1, W2T, eb2, gb2, H2);
  layer3_kernel<<<B_SZ / 32, 256, 0, stream>>>(H2, gW3, gb3, eW3, eb3,
                                               out, out + (size_t)B_SZ * N_CLS);
}